// Round 12
// baseline (467.896 us; speedup 1.0000x reference)
//
#include <hip/hip_runtime.h>

// SurfSageEncoder: 3x SAGEConv(mean) + linear head, fp32.
// N=50000 nodes, E=600000 edges, D: 128 -> 128 -> 128 -> 64 -> 64.
//
// R12 == R11 (never benched: GPU acquisition timeout).
// On top of R10's confirmed-clean runtime-K GEMM (VGPR 52, 61us, 433us total):
//  - k_linear: KT 32->64 (slabs 8->4, barriers 16->8). Runtime K bounds kept
//    (the R3/R5/R8 spill fix: no compile-time unrollable slab loop).
//  - k_agg/k_agg_add: float4 loads + edge-parallel lane groups (2 resp. 4
//    edges in flight per instr), cross-lane fold via __shfl_down. Same bytes,
//    half/quarter the load instructions => more MLP for the gather.

#define BLK 256

// ---------------- CSR build ----------------

__global__ __launch_bounds__(BLK) void k_hist(const int* __restrict__ dst,
                                              int* __restrict__ deg, int E) {
  int i = blockIdx.x * BLK + threadIdx.x;
  int stride = gridDim.x * BLK;
  for (; i < E; i += stride) atomicAdd(&deg[dst[i]], 1);
}

__global__ __launch_bounds__(BLK) void k_scan1(const int* __restrict__ deg,
                                               int* __restrict__ offs,
                                               int* __restrict__ bsums, int n) {
  __shared__ int lds[BLK];
  int t = threadIdx.x;
  int base = blockIdx.x * 1024 + t * 4;
  int v0 = (base + 0 < n) ? deg[base + 0] : 0;
  int v1 = (base + 1 < n) ? deg[base + 1] : 0;
  int v2 = (base + 2 < n) ? deg[base + 2] : 0;
  int v3 = (base + 3 < n) ? deg[base + 3] : 0;
  int s = v0 + v1 + v2 + v3;
  lds[t] = s;
  __syncthreads();
  for (int off = 1; off < BLK; off <<= 1) {
    int x = 0;
    if (t >= off) x = lds[t - off];
    __syncthreads();
    if (t >= off) lds[t] += x;
    __syncthreads();
  }
  int excl = lds[t] - s;
  if (base + 0 < n) offs[base + 0] = excl;
  if (base + 1 < n) offs[base + 1] = excl + v0;
  if (base + 2 < n) offs[base + 2] = excl + v0 + v1;
  if (base + 3 < n) offs[base + 3] = excl + v0 + v1 + v2;
  if (t == BLK - 1) bsums[blockIdx.x] = lds[BLK - 1];
}

__global__ void k_scan2(int* __restrict__ bsums, int nb) {
  if (blockIdx.x == 0 && threadIdx.x == 0) {
    int acc = 0;
    for (int i = 0; i < nb; ++i) { int v = bsums[i]; bsums[i] = acc; acc += v; }
  }
}

__global__ __launch_bounds__(BLK) void k_scan3(int* __restrict__ offs,
                                               const int* __restrict__ bsums,
                                               int* __restrict__ cursor, int n, int E) {
  int i = blockIdx.x * BLK + threadIdx.x;
  if (i < n) {
    int o = offs[i] + bsums[i >> 10];
    offs[i] = o;
    cursor[i] = o;
  }
  if (i == 0) offs[n] = E;
}

__global__ __launch_bounds__(BLK) void k_fill(const int* __restrict__ src,
                                              const int* __restrict__ dst,
                                              int* __restrict__ cursor,
                                              int* __restrict__ csr, int E) {
  int i = blockIdx.x * BLK + threadIdx.x;
  int stride = gridDim.x * BLK;
  for (; i < E; i += stride) {
    int p = atomicAdd(&cursor[dst[i]], 1);
    csr[p] = src[i];
  }
}

// ------------- mean aggregation: one wave/node, 2 edges in flight ----------
// 32 lanes x float4 = one 128-float row; half = lane>>5 selects the edge
// slot, so each wave-instruction gathers 2 rows (4 with the x2 unroll).
// Halves are folded with shfl_down(32); lanes 0-31 write the mean.

__global__ __launch_bounds__(BLK) void k_agg(const float* __restrict__ in,
                                             const int* __restrict__ offs,
                                             const int* __restrict__ csr,
                                             float* __restrict__ outmean, int n) {
  int wid = (blockIdx.x * BLK + threadIdx.x) >> 6;
  int lane = threadIdx.x & 63;
  if (wid >= n) return;
  int beg = offs[wid], end = offs[wid + 1];
  const int half = lane >> 5;
  const int fl = lane & 31;                 // float4 index within row (32 = 128/4)
  const float4* in4 = (const float4*)in;
  float4 s = make_float4(0.f, 0.f, 0.f, 0.f);
  int e = beg + half;
  for (; e + 2 < end; e += 4) {             // 2 edges/half in flight
    int s0 = csr[e], s1 = csr[e + 2];
    float4 a = in4[(size_t)s0 * 32 + fl];
    float4 b = in4[(size_t)s1 * 32 + fl];
    s.x += a.x + b.x; s.y += a.y + b.y; s.z += a.z + b.z; s.w += a.w + b.w;
  }
  for (; e < end; e += 2) {
    float4 a = in4[(size_t)csr[e] * 32 + fl];
    s.x += a.x; s.y += a.y; s.z += a.z; s.w += a.w;
  }
  s.x += __shfl_down(s.x, 32); s.y += __shfl_down(s.y, 32);
  s.z += __shfl_down(s.z, 32); s.w += __shfl_down(s.w, 32);
  if (half == 0) {
    int d = end - beg;
    float inv = 1.0f / (float)(d > 0 ? d : 1);
    float4 r;
    r.x = s.x * inv; r.y = s.y * inv; r.z = s.z * inv; r.w = s.w * inv;
    ((float4*)outmean)[(size_t)wid * 32 + fl] = r;
  }
}

// 64-dim mean-agg of P (cols 0..63 of PQ, row stride 128) plus Q (cols
// 64..127). 16 lanes x float4 = one 64-float P row; q = lane>>4 gives 4 edge
// slots (8 edges in flight with the x2 unroll). Fold 32 then 16.
__global__ __launch_bounds__(BLK) void k_agg_add(const float* __restrict__ PQ,
                                                 const int* __restrict__ offs,
                                                 const int* __restrict__ csr,
                                                 float* __restrict__ outv, int n) {
  int wid = (blockIdx.x * BLK + threadIdx.x) >> 6;
  int lane = threadIdx.x & 63;
  if (wid >= n) return;
  int beg = offs[wid], end = offs[wid + 1];
  const int q = lane >> 4;
  const int fl = lane & 15;                 // float4 index (16 = 64/4)
  const float4* PQ4 = (const float4*)PQ;    // row stride 32 float4
  float4 s = make_float4(0.f, 0.f, 0.f, 0.f);
  int e = beg + q;
  for (; e + 4 < end; e += 8) {             // 2 edges/quarter in flight
    int s0 = csr[e], s1 = csr[e + 4];
    float4 a = PQ4[(size_t)s0 * 32 + fl];
    float4 b = PQ4[(size_t)s1 * 32 + fl];
    s.x += a.x + b.x; s.y += a.y + b.y; s.z += a.z + b.z; s.w += a.w + b.w;
  }
  for (; e < end; e += 4) {
    float4 a = PQ4[(size_t)csr[e] * 32 + fl];
    s.x += a.x; s.y += a.y; s.z += a.z; s.w += a.w;
  }
  s.x += __shfl_down(s.x, 32); s.y += __shfl_down(s.y, 32);
  s.z += __shfl_down(s.z, 32); s.w += __shfl_down(s.w, 32);
  s.x += __shfl_down(s.x, 16); s.y += __shfl_down(s.y, 16);
  s.z += __shfl_down(s.z, 16); s.w += __shfl_down(s.w, 16);
  if (q == 0) {
    int d = end - beg;
    float inv = 1.0f / (float)(d > 0 ? d : 1);
    float4 qv = PQ4[(size_t)wid * 32 + 16 + fl];  // Q half of own row
    float4 r;
    r.x = s.x * inv + qv.x; r.y = s.y * inv + qv.y;
    r.z = s.z * inv + qv.z; r.w = s.w * inv + qv.w;
    ((float4*)outv)[(size_t)wid * 16 + fl] = r;
  }
}

// ---------------- fused linear GEMM (runtime-K loops, KT=64) ---------------
// out[32 rows x COLS] per block. Phase 0: A0@W0^T over runtime K0 (DUAL:
// cols<64 from W0 no-bias, cols>=64 from W1 +bias, both row-stride K0).
// Phase 1 (skipped when K1==0): A1@W1^T. Runtime loop bounds prevent full
// unroll / global-load hoisting (the R3/R5/R8 spill cause). KT=64 halves
// barrier+staging count vs R10. A staged global->reg->LDS As[32][64] (lane
// writes contiguous 16B; compute reads 2-addr broadcast). W staged into
// transposed Bt[64][COLS+4], bj spans 64 distinct values/wave (2-way, free).

template <int COLS, bool RELU, bool DUAL>
__global__ __launch_bounds__(BLK) void k_linear(
    const float* __restrict__ A0, const float* __restrict__ W0, int K0,
    const float* __restrict__ A1, const float* __restrict__ W1, int K1,
    const float* __restrict__ bias, float* __restrict__ out, int M) {
  constexpr int KT = 64;
  constexpr int ROWS = 32;
  constexpr int TC = COLS / 4;            // 32 or 16
  constexpr int TR = BLK / TC;            // 8 or 16
  constexpr int RPT = ROWS / TR;          // 4 or 2
  constexpr int BTS = COLS + 4;           // 16B-aligned, bank-spread
  constexpr int KSPAN = KT * COLS / BLK;  // 32 or 16
  constexpr int F = KSPAN / 4;            // 8 or 4

  __shared__ float As[ROWS * KT];         // 8 KB
  __shared__ float Bt[KT * BTS];          // 33.8 / 17.4 KB

  const int tid = threadIdx.x;
  const int tc = tid % TC, tr = tid / TC;
  const int j0 = tc * 4;
  const int rbase = tr * RPT;
  const int growbase = blockIdx.x * ROWS;

  // A staging: 512 float4s; thread covers #tid (row ar0) and #(tid+256)
  // (row ar0+16), same 16B segment -> coalesced global, contiguous LDS.
  const int ar0 = tid >> 4;               // 0..15
  const int ar1 = ar0 + 16;               // 16..31
  const int asg = tid & 15;               // 16B segment within 64-float row

  // Bt staging
  const int bj = tid % COLS;
  const int kq = (tid / COLS) * KSPAN;

  float4 acc[RPT];
#pragma unroll
  for (int rr = 0; rr < RPT; ++rr) acc[rr] = make_float4(0.f, 0.f, 0.f, 0.f);

  // ---- phase 0: A0 @ W0^T (runtime K0) ----
  for (int k0 = 0; k0 < K0; k0 += KT) {
    {
      const int gr0 = growbase + ar0;
      const int gr1 = growbase + ar1;
      float4 v0 = make_float4(0.f, 0.f, 0.f, 0.f);
      float4 v1 = make_float4(0.f, 0.f, 0.f, 0.f);
      if (gr0 < M) v0 = *(const float4*)&A0[(size_t)gr0 * K0 + k0 + asg * 4];
      if (gr1 < M) v1 = *(const float4*)&A0[(size_t)gr1 * K0 + k0 + asg * 4];
      *(float4*)&As[ar0 * KT + asg * 4] = v0;
      *(float4*)&As[ar1 * KT + asg * 4] = v1;
    }
    {
      const float* Wrow;
      if (DUAL)
        Wrow = (bj < 64) ? (W0 + (size_t)bj * K0) : (W1 + (size_t)(bj - 64) * K0);
      else
        Wrow = W0 + (size_t)bj * K0;
#pragma unroll
      for (int f = 0; f < F; ++f) {
        const float4 w = *(const float4*)&Wrow[k0 + kq + f * 4];
        const int kk = kq + f * 4;
        Bt[(kk + 0) * BTS + bj] = w.x;
        Bt[(kk + 1) * BTS + bj] = w.y;
        Bt[(kk + 2) * BTS + bj] = w.z;
        Bt[(kk + 3) * BTS + bj] = w.w;
      }
    }
    __syncthreads();
#pragma unroll
    for (int kk = 0; kk < KT; kk += 4) {
      float4 a4[RPT];
#pragma unroll
      for (int rr = 0; rr < RPT; ++rr)
        a4[rr] = *(const float4*)&As[(rbase + rr) * KT + kk];
#pragma unroll
      for (int dk = 0; dk < 4; ++dk) {
        const float4 bv = *(const float4*)&Bt[(kk + dk) * BTS + j0];
#pragma unroll
        for (int rr = 0; rr < RPT; ++rr) {
          const float av = (dk == 0)   ? a4[rr].x
                           : (dk == 1) ? a4[rr].y
                           : (dk == 2) ? a4[rr].z
                                       : a4[rr].w;
          acc[rr].x += av * bv.x;
          acc[rr].y += av * bv.y;
          acc[rr].z += av * bv.z;
          acc[rr].w += av * bv.w;
        }
      }
    }
    __syncthreads();
  }

  // ---- phase 1: A1 @ W1^T (runtime K1; trip 0 for DUAL/head) ----
  for (int k0 = 0; k0 < K1; k0 += KT) {
    {
      const int gr0 = growbase + ar0;
      const int gr1 = growbase + ar1;
      float4 v0 = make_float4(0.f, 0.f, 0.f, 0.f);
      float4 v1 = make_float4(0.f, 0.f, 0.f, 0.f);
      if (gr0 < M) v0 = *(const float4*)&A1[(size_t)gr0 * K1 + k0 + asg * 4];
      if (gr1 < M) v1 = *(const float4*)&A1[(size_t)gr1 * K1 + k0 + asg * 4];
      *(float4*)&As[ar0 * KT + asg * 4] = v0;
      *(float4*)&As[ar1 * KT + asg * 4] = v1;
    }
    {
      const float* Wrow = W1 + (size_t)bj * K1;
#pragma unroll
      for (int f = 0; f < F; ++f) {
        const float4 w = *(const float4*)&Wrow[k0 + kq + f * 4];
        const int kk = kq + f * 4;
        Bt[(kk + 0) * BTS + bj] = w.x;
        Bt[(kk + 1) * BTS + bj] = w.y;
        Bt[(kk + 2) * BTS + bj] = w.z;
        Bt[(kk + 3) * BTS + bj] = w.w;
      }
    }
    __syncthreads();
#pragma unroll
    for (int kk = 0; kk < KT; kk += 4) {
      float4 a4[RPT];
#pragma unroll
      for (int rr = 0; rr < RPT; ++rr)
        a4[rr] = *(const float4*)&As[(rbase + rr) * KT + kk];
#pragma unroll
      for (int dk = 0; dk < 4; ++dk) {
        const float4 bv = *(const float4*)&Bt[(kk + dk) * BTS + j0];
#pragma unroll
        for (int rr = 0; rr < RPT; ++rr) {
          const float av = (dk == 0)   ? a4[rr].x
                           : (dk == 1) ? a4[rr].y
                           : (dk == 2) ? a4[rr].z
                                       : a4[rr].w;
          acc[rr].x += av * bv.x;
          acc[rr].y += av * bv.y;
          acc[rr].z += av * bv.z;
          acc[rr].w += av * bv.w;
        }
      }
    }
    __syncthreads();
  }

  float4 bv4 = make_float4(0.f, 0.f, 0.f, 0.f);
  if (!DUAL) {
    bv4 = *(const float4*)&bias[j0];
  } else if (j0 >= 64) {
    bv4 = *(const float4*)&bias[j0 - 64];
  }
#pragma unroll
  for (int rr = 0; rr < RPT; ++rr) {
    const int gr = growbase + rbase + rr;
    if (gr < M) {
      float4 o = acc[rr];
      o.x += bv4.x; o.y += bv4.y; o.z += bv4.z; o.w += bv4.w;
      if (RELU) {
        o.x = fmaxf(o.x, 0.f); o.y = fmaxf(o.y, 0.f);
        o.z = fmaxf(o.z, 0.f); o.w = fmaxf(o.w, 0.f);
      }
      *(float4*)&out[(size_t)gr * COLS + j0] = o;
    }
  }
}

// ---------------- launch ----------------

extern "C" void kernel_launch(void* const* d_in, const int* in_sizes, int n_in,
                              void* d_out, int out_size, void* d_ws, size_t ws_size,
                              hipStream_t stream) {
  const float* x    = (const float*)d_in[0];
  const int*   edge = (const int*)d_in[1];
  const float* Wl1  = (const float*)d_in[2];
  const float* bl1  = (const float*)d_in[3];
  const float* Wr1  = (const float*)d_in[4];
  const float* Wl2  = (const float*)d_in[5];
  const float* bl2  = (const float*)d_in[6];
  const float* Wr2  = (const float*)d_in[7];
  const float* Wl3  = (const float*)d_in[8];
  const float* bl3  = (const float*)d_in[9];
  const float* Wr3  = (const float*)d_in[10];
  const float* Wreg = (const float*)d_in[11];
  const float* breg = (const float*)d_in[12];

  const int N = in_sizes[0] / 128;  // 50000
  const int E = in_sizes[1] / 2;    // 600000
  const int* src = edge;
  const int* dst = edge + E;

  char* ws = (char*)d_ws;
  size_t off = 0;
  auto alloc = [&](size_t bytes) {
    void* p = ws + off;
    off = (off + bytes + 255) & ~(size_t)255;
    return p;
  };
  int*   deg    = (int*)alloc((size_t)N * 4);
  int*   offs   = (int*)alloc((size_t)(N + 1) * 4);
  int*   cursor = (int*)alloc((size_t)N * 4);
  int*   csr    = (int*)alloc((size_t)E * 4);
  int*   bsums  = (int*)alloc(256 * 4);
  float* mean   = (float*)alloc((size_t)N * 128 * 4);  // also PQ buffer (layer 3)
  float* hA     = (float*)alloc((size_t)N * 128 * 4);
  float* hB     = (float*)alloc((size_t)N * 128 * 4);
  (void)ws_size;

  // --- CSR build ---
  hipMemsetAsync(deg, 0, (size_t)N * 4, stream);
  k_hist<<<2048, BLK, 0, stream>>>(dst, deg, E);
  int nb = (N + 1023) >> 10;
  k_scan1<<<nb, BLK, 0, stream>>>(deg, offs, bsums, N);
  k_scan2<<<1, 64, 0, stream>>>(bsums, nb);
  k_scan3<<<(N + BLK - 1) / BLK, BLK, 0, stream>>>(offs, bsums, cursor, N, E);
  k_fill<<<2048, BLK, 0, stream>>>(src, dst, cursor, csr, E);

  const int aggGrid = (N * 64 + BLK - 1) / BLK;
  const int gemmGrid = (N + 31) / 32;   // 32-row tiles

  // --- layer 1: h1 = relu(mean(x)@Wl1^T + x@Wr1^T + bl1) ---
  k_agg<<<aggGrid, BLK, 0, stream>>>(x, offs, csr, mean, N);
  k_linear<128, true, false><<<gemmGrid, BLK, 0, stream>>>(
      mean, Wl1, 128, x, Wr1, 128, bl1, hA, N);

  // --- layer 2 ---
  k_agg<<<aggGrid, BLK, 0, stream>>>(hA, offs, csr, mean, N);
  k_linear<128, true, false><<<gemmGrid, BLK, 0, stream>>>(
      mean, Wl2, 128, hA, Wr2, 128, bl2, hB, N);

  // --- layer 3 (transform-before-aggregate): PQ = [hB@Wl3^T | hB@Wr3^T+bl3] ---
  k_linear<128, false, true><<<gemmGrid, BLK, 0, stream>>>(
      hB, Wl3, 128, (const float*)nullptr, Wr3, 0, bl3, mean, N);
  k_agg_add<<<aggGrid, BLK, 0, stream>>>(mean, offs, csr, hA, N);

  // --- head: out = h3@Wreg^T + breg ---
  k_linear<64, false, false><<<gemmGrid, BLK, 0, stream>>>(
      hA, Wreg, 64, (const float*)nullptr, (const float*)nullptr, 0, breg,
      (float*)d_out, N);
}

// Round 13
// 418.739 us; speedup vs baseline: 1.1174x; 1.1174x over previous
//
#include <hip/hip_runtime.h>

// SurfSageEncoder: 3x SAGEConv(mean) + linear head, fp32.
// N=50000 nodes, E=600000 edges, D: 128 -> 128 -> 128 -> 64 -> 64.
//
// R13 = best-of-each recombination:
//  - k_linear: R10's KT=32 runtime-K version (measured: VGPR 52, 61us,
//    occupancy 28%). R12's KT=64 REGRESSED (42KB LDS -> occupancy 17%,
//    84us): barrier savings < occupancy loss. Runtime K bounds remain the
//    R3/R5/R8 spill fix (no compile-time unrollable slab loop).
//  - k_agg/k_agg_add: R12's float4 + edge-parallel lane groups (measured:
//    ~-35us total vs R10's float2 versions).

#define BLK 256

// ---------------- CSR build ----------------

__global__ __launch_bounds__(BLK) void k_hist(const int* __restrict__ dst,
                                              int* __restrict__ deg, int E) {
  int i = blockIdx.x * BLK + threadIdx.x;
  int stride = gridDim.x * BLK;
  for (; i < E; i += stride) atomicAdd(&deg[dst[i]], 1);
}

__global__ __launch_bounds__(BLK) void k_scan1(const int* __restrict__ deg,
                                               int* __restrict__ offs,
                                               int* __restrict__ bsums, int n) {
  __shared__ int lds[BLK];
  int t = threadIdx.x;
  int base = blockIdx.x * 1024 + t * 4;
  int v0 = (base + 0 < n) ? deg[base + 0] : 0;
  int v1 = (base + 1 < n) ? deg[base + 1] : 0;
  int v2 = (base + 2 < n) ? deg[base + 2] : 0;
  int v3 = (base + 3 < n) ? deg[base + 3] : 0;
  int s = v0 + v1 + v2 + v3;
  lds[t] = s;
  __syncthreads();
  for (int off = 1; off < BLK; off <<= 1) {
    int x = 0;
    if (t >= off) x = lds[t - off];
    __syncthreads();
    if (t >= off) lds[t] += x;
    __syncthreads();
  }
  int excl = lds[t] - s;
  if (base + 0 < n) offs[base + 0] = excl;
  if (base + 1 < n) offs[base + 1] = excl + v0;
  if (base + 2 < n) offs[base + 2] = excl + v0 + v1;
  if (base + 3 < n) offs[base + 3] = excl + v0 + v1 + v2;
  if (t == BLK - 1) bsums[blockIdx.x] = lds[BLK - 1];
}

__global__ void k_scan2(int* __restrict__ bsums, int nb) {
  if (blockIdx.x == 0 && threadIdx.x == 0) {
    int acc = 0;
    for (int i = 0; i < nb; ++i) { int v = bsums[i]; bsums[i] = acc; acc += v; }
  }
}

__global__ __launch_bounds__(BLK) void k_scan3(int* __restrict__ offs,
                                               const int* __restrict__ bsums,
                                               int* __restrict__ cursor, int n, int E) {
  int i = blockIdx.x * BLK + threadIdx.x;
  if (i < n) {
    int o = offs[i] + bsums[i >> 10];
    offs[i] = o;
    cursor[i] = o;
  }
  if (i == 0) offs[n] = E;
}

__global__ __launch_bounds__(BLK) void k_fill(const int* __restrict__ src,
                                              const int* __restrict__ dst,
                                              int* __restrict__ cursor,
                                              int* __restrict__ csr, int E) {
  int i = blockIdx.x * BLK + threadIdx.x;
  int stride = gridDim.x * BLK;
  for (; i < E; i += stride) {
    int p = atomicAdd(&cursor[dst[i]], 1);
    csr[p] = src[i];
  }
}

// ------------- mean aggregation: one wave/node, 2 edges in flight ----------
// 32 lanes x float4 = one 128-float row; half = lane>>5 selects the edge
// slot, so each wave-instruction gathers 2 rows (4 with the x2 unroll).
// Halves are folded with shfl_down(32); lanes 0-31 write the mean.

__global__ __launch_bounds__(BLK) void k_agg(const float* __restrict__ in,
                                             const int* __restrict__ offs,
                                             const int* __restrict__ csr,
                                             float* __restrict__ outmean, int n) {
  int wid = (blockIdx.x * BLK + threadIdx.x) >> 6;
  int lane = threadIdx.x & 63;
  if (wid >= n) return;
  int beg = offs[wid], end = offs[wid + 1];
  const int half = lane >> 5;
  const int fl = lane & 31;                 // float4 index within row (32 = 128/4)
  const float4* in4 = (const float4*)in;
  float4 s = make_float4(0.f, 0.f, 0.f, 0.f);
  int e = beg + half;
  for (; e + 2 < end; e += 4) {             // 2 edges/half in flight
    int s0 = csr[e], s1 = csr[e + 2];
    float4 a = in4[(size_t)s0 * 32 + fl];
    float4 b = in4[(size_t)s1 * 32 + fl];
    s.x += a.x + b.x; s.y += a.y + b.y; s.z += a.z + b.z; s.w += a.w + b.w;
  }
  for (; e < end; e += 2) {
    float4 a = in4[(size_t)csr[e] * 32 + fl];
    s.x += a.x; s.y += a.y; s.z += a.z; s.w += a.w;
  }
  s.x += __shfl_down(s.x, 32); s.y += __shfl_down(s.y, 32);
  s.z += __shfl_down(s.z, 32); s.w += __shfl_down(s.w, 32);
  if (half == 0) {
    int d = end - beg;
    float inv = 1.0f / (float)(d > 0 ? d : 1);
    float4 r;
    r.x = s.x * inv; r.y = s.y * inv; r.z = s.z * inv; r.w = s.w * inv;
    ((float4*)outmean)[(size_t)wid * 32 + fl] = r;
  }
}

// 64-dim mean-agg of P (cols 0..63 of PQ, row stride 128) plus Q (cols
// 64..127). 16 lanes x float4 = one 64-float P row; q = lane>>4 gives 4 edge
// slots (8 edges in flight with the x2 unroll). Fold 32 then 16.
__global__ __launch_bounds__(BLK) void k_agg_add(const float* __restrict__ PQ,
                                                 const int* __restrict__ offs,
                                                 const int* __restrict__ csr,
                                                 float* __restrict__ outv, int n) {
  int wid = (blockIdx.x * BLK + threadIdx.x) >> 6;
  int lane = threadIdx.x & 63;
  if (wid >= n) return;
  int beg = offs[wid], end = offs[wid + 1];
  const int q = lane >> 4;
  const int fl = lane & 15;                 // float4 index (16 = 64/4)
  const float4* PQ4 = (const float4*)PQ;    // row stride 32 float4
  float4 s = make_float4(0.f, 0.f, 0.f, 0.f);
  int e = beg + q;
  for (; e + 4 < end; e += 8) {             // 2 edges/quarter in flight
    int s0 = csr[e], s1 = csr[e + 4];
    float4 a = PQ4[(size_t)s0 * 32 + fl];
    float4 b = PQ4[(size_t)s1 * 32 + fl];
    s.x += a.x + b.x; s.y += a.y + b.y; s.z += a.z + b.z; s.w += a.w + b.w;
  }
  for (; e < end; e += 4) {
    float4 a = PQ4[(size_t)csr[e] * 32 + fl];
    s.x += a.x; s.y += a.y; s.z += a.z; s.w += a.w;
  }
  s.x += __shfl_down(s.x, 32); s.y += __shfl_down(s.y, 32);
  s.z += __shfl_down(s.z, 32); s.w += __shfl_down(s.w, 32);
  s.x += __shfl_down(s.x, 16); s.y += __shfl_down(s.y, 16);
  s.z += __shfl_down(s.z, 16); s.w += __shfl_down(s.w, 16);
  if (q == 0) {
    int d = end - beg;
    float inv = 1.0f / (float)(d > 0 ? d : 1);
    float4 qv = PQ4[(size_t)wid * 32 + 16 + fl];  // Q half of own row
    float4 r;
    r.x = s.x * inv + qv.x; r.y = s.y * inv + qv.y;
    r.z = s.z * inv + qv.z; r.w = s.w * inv + qv.w;
    ((float4*)outv)[(size_t)wid * 16 + fl] = r;
  }
}

// ---------------- fused linear GEMM (runtime-K loops, KT=32) ---------------
// out[32 rows x COLS] per block. Phase 0: A0@W0^T over runtime K0 (DUAL:
// cols<64 from W0 no-bias, cols>=64 from W1 +bias, both row-stride K0).
// Phase 1 (skipped when K1==0): A1@W1^T over runtime K1. Runtime loop bounds
// prevent full unroll / global-load hoisting (the R3/R5/R8 spill cause).
// A staged global->reg->LDS As[32][32]: lane writes contiguous 16B (conflict-
// free); compute reads are 2-addr broadcasts. W staged into transposed
// Bt[32][COLS+4], j=tid%COLS (measured 0 conflicts). KT=64 tried in R12:
// regressed (42KB LDS -> occupancy 17%, 84us vs 61us) — do not revisit.

template <int COLS, bool RELU, bool DUAL>
__global__ __launch_bounds__(BLK) void k_linear(
    const float* __restrict__ A0, const float* __restrict__ W0, int K0,
    const float* __restrict__ A1, const float* __restrict__ W1, int K1,
    const float* __restrict__ bias, float* __restrict__ out, int M) {
  constexpr int KT = 32;
  constexpr int ROWS = 32;
  constexpr int TC = COLS / 4;            // 32 or 16
  constexpr int TR = BLK / TC;            // 8 or 16
  constexpr int RPT = ROWS / TR;          // 4 or 2
  constexpr int BTS = COLS + 4;           // 16B-aligned, bank-spread
  constexpr int KSPAN = KT * COLS / BLK;  // 16 or 8
  constexpr int F = KSPAN / 4;            // 4 or 2

  __shared__ float As[ROWS * KT];         // 4 KB
  __shared__ float Bt[KT * BTS];          // 16.5/8.5 KB

  const int tid = threadIdx.x;
  const int tc = tid % TC, tr = tid / TC;
  const int j0 = tc * 4;
  const int rbase = tr * RPT;
  const int growbase = blockIdx.x * ROWS;

  // A staging: thread t covers float4 #t of the 256-float4 tile (contiguous)
  const int arow = tid >> 3;              // 0..31
  const int asg = tid & 7;                // 16B segment within row

  // Bt staging
  const int bj = tid % COLS;
  const int kq = (tid / COLS) * KSPAN;

  float4 acc[RPT];
#pragma unroll
  for (int rr = 0; rr < RPT; ++rr) acc[rr] = make_float4(0.f, 0.f, 0.f, 0.f);

  // ---- phase 0: A0 @ W0^T (runtime K0) ----
  for (int k0 = 0; k0 < K0; k0 += KT) {
    {
      const int gr = growbase + arow;
      float4 v = make_float4(0.f, 0.f, 0.f, 0.f);
      if (gr < M) v = *(const float4*)&A0[(size_t)gr * K0 + k0 + asg * 4];
      *(float4*)&As[arow * KT + asg * 4] = v;
    }
    {
      const float* Wrow;
      if (DUAL)
        Wrow = (bj < 64) ? (W0 + (size_t)bj * K0) : (W1 + (size_t)(bj - 64) * K0);
      else
        Wrow = W0 + (size_t)bj * K0;
#pragma unroll
      for (int f = 0; f < F; ++f) {
        const float4 w = *(const float4*)&Wrow[k0 + kq + f * 4];
        const int kk = kq + f * 4;
        Bt[(kk + 0) * BTS + bj] = w.x;
        Bt[(kk + 1) * BTS + bj] = w.y;
        Bt[(kk + 2) * BTS + bj] = w.z;
        Bt[(kk + 3) * BTS + bj] = w.w;
      }
    }
    __syncthreads();
#pragma unroll
    for (int kk = 0; kk < KT; kk += 4) {
      float4 a4[RPT];
#pragma unroll
      for (int rr = 0; rr < RPT; ++rr)
        a4[rr] = *(const float4*)&As[(rbase + rr) * KT + kk];
#pragma unroll
      for (int dk = 0; dk < 4; ++dk) {
        const float4 bv = *(const float4*)&Bt[(kk + dk) * BTS + j0];
#pragma unroll
        for (int rr = 0; rr < RPT; ++rr) {
          const float av = (dk == 0)   ? a4[rr].x
                           : (dk == 1) ? a4[rr].y
                           : (dk == 2) ? a4[rr].z
                                       : a4[rr].w;
          acc[rr].x += av * bv.x;
          acc[rr].y += av * bv.y;
          acc[rr].z += av * bv.z;
          acc[rr].w += av * bv.w;
        }
      }
    }
    __syncthreads();
  }

  // ---- phase 1: A1 @ W1^T (runtime K1; trip 0 for DUAL/head) ----
  for (int k0 = 0; k0 < K1; k0 += KT) {
    {
      const int gr = growbase + arow;
      float4 v = make_float4(0.f, 0.f, 0.f, 0.f);
      if (gr < M) v = *(const float4*)&A1[(size_t)gr * K1 + k0 + asg * 4];
      *(float4*)&As[arow * KT + asg * 4] = v;
    }
    {
      const float* Wrow = W1 + (size_t)bj * K1;
#pragma unroll
      for (int f = 0; f < F; ++f) {
        const float4 w = *(const float4*)&Wrow[k0 + kq + f * 4];
        const int kk = kq + f * 4;
        Bt[(kk + 0) * BTS + bj] = w.x;
        Bt[(kk + 1) * BTS + bj] = w.y;
        Bt[(kk + 2) * BTS + bj] = w.z;
        Bt[(kk + 3) * BTS + bj] = w.w;
      }
    }
    __syncthreads();
#pragma unroll
    for (int kk = 0; kk < KT; kk += 4) {
      float4 a4[RPT];
#pragma unroll
      for (int rr = 0; rr < RPT; ++rr)
        a4[rr] = *(const float4*)&As[(rbase + rr) * KT + kk];
#pragma unroll
      for (int dk = 0; dk < 4; ++dk) {
        const float4 bv = *(const float4*)&Bt[(kk + dk) * BTS + j0];
#pragma unroll
        for (int rr = 0; rr < RPT; ++rr) {
          const float av = (dk == 0)   ? a4[rr].x
                           : (dk == 1) ? a4[rr].y
                           : (dk == 2) ? a4[rr].z
                                       : a4[rr].w;
          acc[rr].x += av * bv.x;
          acc[rr].y += av * bv.y;
          acc[rr].z += av * bv.z;
          acc[rr].w += av * bv.w;
        }
      }
    }
    __syncthreads();
  }

  float4 bv4 = make_float4(0.f, 0.f, 0.f, 0.f);
  if (!DUAL) {
    bv4 = *(const float4*)&bias[j0];
  } else if (j0 >= 64) {
    bv4 = *(const float4*)&bias[j0 - 64];
  }
#pragma unroll
  for (int rr = 0; rr < RPT; ++rr) {
    const int gr = growbase + rbase + rr;
    if (gr < M) {
      float4 o = acc[rr];
      o.x += bv4.x; o.y += bv4.y; o.z += bv4.z; o.w += bv4.w;
      if (RELU) {
        o.x = fmaxf(o.x, 0.f); o.y = fmaxf(o.y, 0.f);
        o.z = fmaxf(o.z, 0.f); o.w = fmaxf(o.w, 0.f);
      }
      *(float4*)&out[(size_t)gr * COLS + j0] = o;
    }
  }
}

// ---------------- launch ----------------

extern "C" void kernel_launch(void* const* d_in, const int* in_sizes, int n_in,
                              void* d_out, int out_size, void* d_ws, size_t ws_size,
                              hipStream_t stream) {
  const float* x    = (const float*)d_in[0];
  const int*   edge = (const int*)d_in[1];
  const float* Wl1  = (const float*)d_in[2];
  const float* bl1  = (const float*)d_in[3];
  const float* Wr1  = (const float*)d_in[4];
  const float* Wl2  = (const float*)d_in[5];
  const float* bl2  = (const float*)d_in[6];
  const float* Wr2  = (const float*)d_in[7];
  const float* Wl3  = (const float*)d_in[8];
  const float* bl3  = (const float*)d_in[9];
  const float* Wr3  = (const float*)d_in[10];
  const float* Wreg = (const float*)d_in[11];
  const float* breg = (const float*)d_in[12];

  const int N = in_sizes[0] / 128;  // 50000
  const int E = in_sizes[1] / 2;    // 600000
  const int* src = edge;
  const int* dst = edge + E;

  char* ws = (char*)d_ws;
  size_t off = 0;
  auto alloc = [&](size_t bytes) {
    void* p = ws + off;
    off = (off + bytes + 255) & ~(size_t)255;
    return p;
  };
  int*   deg    = (int*)alloc((size_t)N * 4);
  int*   offs   = (int*)alloc((size_t)(N + 1) * 4);
  int*   cursor = (int*)alloc((size_t)N * 4);
  int*   csr    = (int*)alloc((size_t)E * 4);
  int*   bsums  = (int*)alloc(256 * 4);
  float* mean   = (float*)alloc((size_t)N * 128 * 4);  // also PQ buffer (layer 3)
  float* hA     = (float*)alloc((size_t)N * 128 * 4);
  float* hB     = (float*)alloc((size_t)N * 128 * 4);
  (void)ws_size;

  // --- CSR build ---
  hipMemsetAsync(deg, 0, (size_t)N * 4, stream);
  k_hist<<<2048, BLK, 0, stream>>>(dst, deg, E);
  int nb = (N + 1023) >> 10;
  k_scan1<<<nb, BLK, 0, stream>>>(deg, offs, bsums, N);
  k_scan2<<<1, 64, 0, stream>>>(bsums, nb);
  k_scan3<<<(N + BLK - 1) / BLK, BLK, 0, stream>>>(offs, bsums, cursor, N, E);
  k_fill<<<2048, BLK, 0, stream>>>(src, dst, cursor, csr, E);

  const int aggGrid = (N * 64 + BLK - 1) / BLK;
  const int gemmGrid = (N + 31) / 32;   // 32-row tiles

  // --- layer 1: h1 = relu(mean(x)@Wl1^T + x@Wr1^T + bl1) ---
  k_agg<<<aggGrid, BLK, 0, stream>>>(x, offs, csr, mean, N);
  k_linear<128, true, false><<<gemmGrid, BLK, 0, stream>>>(
      mean, Wl1, 128, x, Wr1, 128, bl1, hA, N);

  // --- layer 2 ---
  k_agg<<<aggGrid, BLK, 0, stream>>>(hA, offs, csr, mean, N);
  k_linear<128, true, false><<<gemmGrid, BLK, 0, stream>>>(
      mean, Wl2, 128, hA, Wr2, 128, bl2, hB, N);

  // --- layer 3 (transform-before-aggregate): PQ = [hB@Wl3^T | hB@Wr3^T+bl3] ---
  k_linear<128, false, true><<<gemmGrid, BLK, 0, stream>>>(
      hB, Wl3, 128, (const float*)nullptr, Wr3, 0, bl3, mean, N);
  k_agg_add<<<aggGrid, BLK, 0, stream>>>(mean, offs, csr, hA, N);

  // --- head: out = h3@Wreg^T + breg ---
  k_linear<64, false, false><<<gemmGrid, BLK, 0, stream>>>(
      hA, Wreg, 64, (const float*)nullptr, (const float*)nullptr, 0, breg,
      (float*)d_out, N);
}